// Round 11
// baseline (163.053 us; speedup 1.0000x reference)
//
#include <hip/hip_runtime.h>

#define SLEN 1024
#define BATCH 2
#define DEPTH 6

typedef _Float16 h8 __attribute__((ext_vector_type(8)));
typedef float    f4 __attribute__((ext_vector_type(4)));
typedef float    f16f __attribute__((ext_vector_type(16)));
#define MF16(a, b, c) __builtin_amdgcn_mfma_f32_16x16x32_f16(a, b, c, 0, 0, 0)
#define MF32(a, b, c) __builtin_amdgcn_mfma_f32_32x32x16_f16(a, b, c, 0, 0, 0)

// logical chunk <-> stored chunk swizzle (8 chunks of 8 halfs per 64-half row)
#define SW(row, c) ((((c) ^ ((row) & 7))) * 8)

// async global->LDS, 16B per lane; LDS dest = wave-uniform base + lane*16
__device__ __forceinline__ void async_cp16(const _Float16* g, _Float16* l) {
  __builtin_amdgcn_global_load_lds(
      (const __attribute__((address_space(1))) void*)g,
      (__attribute__((address_space(3))) void*)l, 16, 0, 0);
}

// ---------------------------------------------------------------------------
// prep: bid 0..1023 x->fp16 ; 1024..2047 weight transpose+convert ;
//       2048..2303 mask bit-pack
// ---------------------------------------------------------------------------
__global__ __launch_bounds__(256) void prep(const float* __restrict__ x,
    const float* __restrict__ wq, const float* __restrict__ wk,
    const float* __restrict__ wv, const float* __restrict__ wo,
    const int* __restrict__ masks, _Float16* __restrict__ xh,
    _Float16* __restrict__ qt, _Float16* __restrict__ kt,
    _Float16* __restrict__ vt, _Float16* __restrict__ ot,
    unsigned int* __restrict__ mpk) {
  __shared__ _Float16 T[64][72];
  const int bid = blockIdx.x, t = threadIdx.x;
  if (bid < 1024) {
    int idx = (bid * 256 + t) * 8;
    float4 f0 = *(const float4*)(x + idx);
    float4 f1 = *(const float4*)(x + idx + 4);
    union { h8 v; _Float16 e[8]; } u;
    u.e[0] = (_Float16)f0.x; u.e[1] = (_Float16)f0.y;
    u.e[2] = (_Float16)f0.z; u.e[3] = (_Float16)f0.w;
    u.e[4] = (_Float16)f1.x; u.e[5] = (_Float16)f1.y;
    u.e[6] = (_Float16)f1.z; u.e[7] = (_Float16)f1.w;
    *(h8*)(xh + idx) = u.v;
  } else if (bid < 2048) {
    const int i = bid - 1024;
    const int wsel = i >> 8;
    const float* W = wsel == 0 ? wq : wsel == 1 ? wk : wsel == 2 ? wv : wo;
    _Float16* O = wsel == 0 ? qt : wsel == 1 ? kt : wsel == 2 ? vt : ot;
    const int k0 = ((i >> 4) & 15) * 64, n0 = (i & 15) * 64;
    const int rr = t >> 2, cs = (t & 3) * 16;
    #pragma unroll
    for (int j = 0; j < 4; ++j) {
      float4 f = *(const float4*)(W + (size_t)(k0 + rr) * 1024 + n0 + cs + j * 4);
      T[rr][cs + j * 4 + 0] = (_Float16)f.x;
      T[rr][cs + j * 4 + 1] = (_Float16)f.y;
      T[rr][cs + j * 4 + 2] = (_Float16)f.z;
      T[rr][cs + j * 4 + 3] = (_Float16)f.w;
    }
    __syncthreads();
    const int n = t >> 2, ks = (t & 3) * 16;
    union { h8 v; _Float16 e[8]; } u0, u1;
    #pragma unroll
    for (int j = 0; j < 8; ++j) { u0.e[j] = T[ks + j][n]; u1.e[j] = T[ks + 8 + j][n]; }
    *(h8*)(O + (size_t)(n0 + n) * 1024 + k0 + ks)     = u0.v;
    *(h8*)(O + (size_t)(n0 + n) * 1024 + k0 + ks + 8) = u1.v;
  } else {
    const int g = (bid - 2048) * 256 + t;
    const int row = g >> 5, w = g & 31;
    const int* m = masks + (size_t)row * 1024 + w * 32;
    unsigned int bits = 0;
    #pragma unroll
    for (int j4 = 0; j4 < 8; ++j4) {
      int4 mm = *(const int4*)(m + j4 * 4);
      if (mm.x) bits |= 1u << (j4 * 4 + 0);
      if (mm.y) bits |= 1u << (j4 * 4 + 1);
      if (mm.z) bits |= 1u << (j4 * 4 + 2);
      if (mm.w) bits |= 1u << (j4 * 4 + 3);
    }
    mpk[g] = bits;
  }
}

// ---------------------------------------------------------------------------
// fp16 MFMA GEMM, 64x128 tile, BK=64, SINGLE-buffer async-LDS staging,
// 2 barriers per K-chunk (r9/r10 proven). TMODE 0/1/2 as r10.
// ---------------------------------------------------------------------------
template <int TMODE, typename CT>
__device__ __forceinline__ void gemm16(const _Float16* __restrict__ A,
                                       const _Float16* __restrict__ Bt,
                                       CT* __restrict__ C,
                                       const int* __restrict__ Hm,
                                       const int* __restrict__ Bm,
                                       _Float16* __restrict__ SH,
                                       const float* __restrict__ FR) {
  _Float16* As = SH;            // 4096 halfs: 64 rows x 64
  _Float16* Bs = SH + 4096;     // 8192 halfs: 128 rows x 64
  const int t    = threadIdx.x;
  const int bm   = blockIdx.y * 64, bn = blockIdx.x * 128;
  const int w    = t >> 6, lane = t & 63;
  const int ln15 = lane & 15, quad = lane >> 4;
  const int wm   = (w >> 1) * 32, wn = (w & 1) * 64;

  const int srow8 = lane >> 3;
  const int sch   = (lane & 7) ^ srow8;
  const _Float16* agp = A  + (size_t)(bm + w * 16 + srow8) * 1024 + sch * 8;
  const _Float16* bgp = Bt + (size_t)(bn + w * 32 + srow8) * 1024 + sch * 8;

  f4 acc[2][4];
  #pragma unroll
  for (int i = 0; i < 2; ++i)
    #pragma unroll
    for (int j = 0; j < 4; ++j) acc[i][j] = (f4){0.f, 0.f, 0.f, 0.f};

  for (int k0 = 0; k0 < 1024; k0 += 64) {
    #pragma unroll
    for (int j = 0; j < 2; ++j)
      async_cp16(agp + k0 + j * 8192, As + w * 1024 + j * 512);
    #pragma unroll
    for (int j = 0; j < 4; ++j)
      async_cp16(bgp + k0 + j * 8192, Bs + w * 2048 + j * 512);
    __syncthreads();
    #pragma unroll
    for (int kk = 0; kk < 8; kk += 4) {
      h8 af[2], bf[4];
      #pragma unroll
      for (int i = 0; i < 2; ++i) {
        int row = wm + i * 16 + ln15;
        af[i] = *(const h8*)&As[row * 64 + SW(row, kk + quad)];
      }
      #pragma unroll
      for (int j = 0; j < 4; ++j) {
        int row = wn + j * 16 + ln15;
        bf[j] = *(const h8*)&Bs[row * 64 + SW(row, kk + quad)];
      }
      #pragma unroll
      for (int i = 0; i < 2; ++i)
        #pragma unroll
        for (int j = 0; j < 4; ++j)
          acc[i][j] = MF16(af[i], bf[j], acc[i][j]);
    }
    __syncthreads();
  }

  if (TMODE == 0) {
    #pragma unroll
    for (int i = 0; i < 2; ++i) {
      int row = bm + wm + i * 16 + quad * 4;
      #pragma unroll
      for (int r = 0; r < 4; ++r)
        #pragma unroll
        for (int j = 0; j < 4; ++j)
          C[(size_t)(row + r) * 1024 + bn + wn + j * 16 + ln15] = (CT)acc[i][j][r];
    }
  } else if (TMODE == 1) {
    #pragma unroll
    for (int i = 0; i < 2; ++i) {
      int m0 = bm + wm + i * 16 + quad * 4;
      #pragma unroll
      for (int r = 0; r < 4; ++r) {
        int m = m0 + r;
        size_t base = ((size_t)(m >> 10) * 1024) * 1024 + (m & 1023);
        #pragma unroll
        for (int j = 0; j < 4; ++j)
          C[base + (size_t)(bn + wn + j * 16 + ln15) * 1024] = (CT)acc[i][j][r];
      }
    }
  } else {
    _Float16* EP = SH;
    #pragma unroll
    for (int i = 0; i < 2; ++i)
      #pragma unroll
      for (int j = 0; j < 4; ++j) {
        int cl = wn + j * 16 + ln15;
        #pragma unroll
        for (int r = 0; r < 4; ++r) {
          int rl = wm + i * 16 + quad * 4 + r;
          EP[rl * 128 + (((cl >> 3) ^ (rl & 15)) << 3) + (cl & 7)] =
              (_Float16)acc[i][j][r];
        }
      }
    __syncthreads();
    const int row = t >> 2, head = (t >> 1) & 1, p = t & 1;
    const int bs = bm + row;
    const int r15 = row & 15;
    float vv[32];
    #pragma unroll
    for (int cc = 0; cc < 4; ++cc) {
      int lc = head * 8 + 2 * p + (cc & 1) + (cc >> 1) * 4;
      union { h8 v; _Float16 e[8]; } u;
      u.v = *(const h8*)&EP[row * 128 + (lc ^ r15) * 8];
      #pragma unroll
      for (int e = 0; e < 8; ++e) vv[cc * 8 + e] = (float)u.e[e];
    }
    #pragma unroll 1
    for (int d = 0; d < DEPTH; ++d) {
      if (Hm[d * (BATCH * SLEN) + bs] != 0) {
        #pragma unroll
        for (int jj = 0; jj < 8; ++jj) {
          int j0 = 8 * p + jj, j1 = 16 + 8 * p + jj;
          float re0 = vv[2 * jj], im0 = vv[2 * jj + 1];
          vv[2 * jj]     = re0 * FR[j0] - im0 * FR[32 + j0];
          vv[2 * jj + 1] = re0 * FR[32 + j0] + im0 * FR[j0];
          float re1 = vv[16 + 2 * jj], im1 = vv[17 + 2 * jj];
          vv[16 + 2 * jj] = re1 * FR[j1] - im1 * FR[32 + j1];
          vv[17 + 2 * jj] = re1 * FR[32 + j1] + im1 * FR[j1];
        }
      }
      if (Bm[(d * 2 + 0) * (BATCH * SLEN) + bs] != 0) {
        #pragma unroll
        for (int jj = 0; jj < 16; ++jj) {
          int j = 16 * p + jj;
          float re = vv[jj], im = vv[16 + jj];
          vv[jj]      = re * FR[j] - im * FR[32 + j];
          vv[16 + jj] = re * FR[32 + j] + im * FR[j];
        }
      }
      if (Bm[(d * 2 + 1) * (BATCH * SLEN) + bs] != 0) {
        #pragma unroll
        for (int jj = 0; jj < 16; ++jj) {
          int j = 16 * p + jj;
          float re = vv[jj], im = vv[16 + jj];
          vv[jj]      = re * FR[64 + j] - im * FR[96 + j];
          vv[16 + jj] = re * FR[96 + j] + im * FR[64 + j];
        }
      }
    }
    _Float16* dst = (_Float16*)C + (size_t)(bm + row) * 1024 + bn + head * 64;
    #pragma unroll
    for (int cc = 0; cc < 4; ++cc) {
      union { h8 v; _Float16 e[8]; } u;
      #pragma unroll
      for (int e = 0; e < 8; ++e) u.e[e] = (_Float16)vv[cc * 8 + e];
      int off = (cc < 2) ? (16 * p + cc * 8) : (32 + 16 * p + (cc - 2) * 8);
      *(h8*)(dst + off) = u.v;
    }
  }
}

__global__ __launch_bounds__(256) void gemm_qkv16(
    const _Float16* __restrict__ xh, const _Float16* __restrict__ qt,
    const _Float16* __restrict__ kt, const _Float16* __restrict__ vtw,
    _Float16* __restrict__ q, _Float16* __restrict__ k,
    _Float16* __restrict__ vth, const int* __restrict__ Hm,
    const int* __restrict__ Bm, const float* __restrict__ fc,
    const float* __restrict__ fs) {
  __shared__ _Float16 SH[12288];
  __shared__ float FR[128];
  if (blockIdx.z != 2 && threadIdx.x < 128) {
    int g = threadIdx.x & 31;
    FR[threadIdx.x] = (threadIdx.x < 32) ? fc[32 + g]
                    : (threadIdx.x < 64) ? fs[32 + g]
                    : (threadIdx.x < 96) ? fc[64 + g] : fs[64 + g];
  }
  if (blockIdx.z == 2)
    gemm16<1, _Float16>(xh, vtw, vth, nullptr, nullptr, SH, nullptr);
  else if (blockIdx.z == 1)
    gemm16<2, _Float16>(xh, kt, k, Hm, Bm, SH, FR);
  else
    gemm16<2, _Float16>(xh, qt, q, Hm, Bm, SH, FR);
}

__global__ __launch_bounds__(256) void gemm_o16(
    const _Float16* __restrict__ A, const _Float16* __restrict__ Bt,
    float* __restrict__ C) {
  __shared__ _Float16 SH[12288];
  gemm16<0, float>(A, Bt, C, nullptr, nullptr, SH, nullptr);
}

// ---------------------------------------------------------------------------
// MFMA flash attention with 32x32x16 MFMAs. Block = (b,h,64 q-rows), 4 waves:
// wave w -> q-half (w&1)*32, k-half (w>>1)*32 of each 64-col chunk.
// K/V staged dbuf async (r10 proven). Fixed-max softmax p=exp(s/8-3);
// per-wave k-half partials (O, l) combined once in epilogue via LDS.
// A/B frag: m(or n)=lane&31, k=(lane>>5)*8+j. C/D: col=lane&31,
// row=(reg&3)+8*(reg>>2)+4*(lane>>5).
// ---------------------------------------------------------------------------
__global__ __launch_bounds__(256) void attn_mfma(const _Float16* __restrict__ qh,
    const _Float16* __restrict__ kh, const _Float16* __restrict__ vth,
    const unsigned int* __restrict__ mpk, _Float16* __restrict__ out) {
  __shared__ _Float16 Ks[2][4096];   // [64][64] swizzled, dbuf (16KB)
  __shared__ _Float16 Vs[2][4096];   // (16KB)
  __shared__ _Float16 PB[4][1280];   // per-wave P: 32 rows x stride 40 (10KB)

  const int t    = threadIdx.x;
  const int w    = t >> 6, lane = t & 63;
  const int l31  = lane & 31, hh = lane >> 5;
  const int qh32 = (w & 1) * 32;     // q-row offset within block
  const int kh32 = (w >> 1) * 32;    // k-col offset within chunk

  const int bh = blockIdx.x & 31;    // same (b,h) -> same XCD
  const int s0 = (blockIdx.x >> 5) * 64;
  const int b = bh >> 4, h = bh & 15;
  const size_t qkbase = (size_t)b * (SLEN * 1024) + h * 64;
  const size_t vbase  = ((size_t)b * 1024 + h * 64) * SLEN;

  // ---- stage Q (row-swizzled) into Ks[0], read fragments ----
  {
    const int srow = t >> 2, c0 = (t & 3) * 2;
    const _Float16* src = qh + qkbase + (size_t)(s0 + srow) * 1024 + c0 * 8;
    h8 q0 = *(const h8*)src;
    h8 q1 = *(const h8*)(src + 8);
    *(h8*)&Ks[0][srow * 64 + SW(srow, c0)]     = q0;
    *(h8*)&Ks[0][srow * 64 + SW(srow, c0 + 1)] = q1;
  }
  __syncthreads();
  h8 qf[4];
  #pragma unroll
  for (int kg = 0; kg < 4; ++kg) {
    int row = qh32 + l31;
    qf[kg] = *(const h8*)&Ks[0][row * 64 + SW(row, kg * 2 + hh)];
  }
  __syncthreads();   // all Q reads done before chunk-0 staging lands in Ks[0]

  // staging lane map (identical to r10)
  const int srow8 = lane >> 3;
  const int sch   = (lane & 7) ^ srow8;
  const _Float16* kgp = kh + qkbase + (size_t)(w * 16 + srow8) * 1024 + sch * 8;
  const _Float16* vgp = vth + vbase + (size_t)(w * 16 + srow8) * 1024 + sch * 8;

  // mask base: rows s0+qh32+4*hh+..., word column kh32/32 within each chunk
  const unsigned int* mp =
      mpk + ((size_t)b * SLEN + s0 + qh32 + 4 * hh) * 32 + (kh32 >> 5);

  float lrow[16];
  #pragma unroll
  for (int r = 0; r < 16; ++r) lrow[r] = 1e-30f;
  f16f o0, o1;
  #pragma unroll
  for (int r = 0; r < 16; ++r) { o0[r] = 0.f; o1[r] = 0.f; }

  // prologue: stage chunk 0 + mask words
  async_cp16(kgp,        &Ks[0][w * 1024]);
  async_cp16(kgp + 8192, &Ks[0][w * 1024 + 512]);
  async_cp16(vgp,        &Vs[0][w * 1024]);
  async_cp16(vgp + 8192, &Vs[0][w * 1024 + 512]);
  unsigned int mw[16];
  #pragma unroll
  for (int r = 0; r < 16; ++r) mw[r] = mp[((r & 3) + 8 * (r >> 2)) * 32];
  __syncthreads();

  for (int c = 0; c < 16; ++c) {
    const int cur = c & 1;
    unsigned int nmw[16];
    if (c < 15) {
      const size_t ko = (size_t)((c + 1) * 64) * 1024;
      const int    vo = (c + 1) * 64;
      async_cp16(kgp + ko,        &Ks[cur ^ 1][w * 1024]);
      async_cp16(kgp + ko + 8192, &Ks[cur ^ 1][w * 1024 + 512]);
      async_cp16(vgp + vo,        &Vs[cur ^ 1][w * 1024]);
      async_cp16(vgp + vo + 8192, &Vs[cur ^ 1][w * 1024 + 512]);
      #pragma unroll
      for (int r = 0; r < 16; ++r)
        nmw[r] = mp[((r & 3) + 8 * (r >> 2)) * 32 + (c + 1) * 2];
    }

    // ---- S = Q K^T  (32 q x 32 k, contraction over 64 dims) ----
    f16f s;
    #pragma unroll
    for (int r = 0; r < 16; ++r) s[r] = 0.f;
    #pragma unroll
    for (int kg = 0; kg < 4; ++kg) {
      int row = kh32 + l31;
      h8 kf = *(const h8*)&Ks[cur][row * 64 + SW(row, kg * 2 + hh)];
      s = MF32(qf[kg], kf, s);
    }
    // ---- masked exp, P store, l accumulate ----
    #pragma unroll
    for (int r = 0; r < 16; ++r) {
      float p = ((mw[r] >> l31) & 1u)
                  ? __expf(s[r] * 0.125f - 3.0f) : 0.0f;
      lrow[r] += p;
      PB[w][((r & 3) + 8 * (r >> 2) + 4 * hh) * 40 + l31] = (_Float16)p;
    }
    // ---- O += P V  (per-wave k-half partial) ----
    h8 pf0 = *(const h8*)&PB[w][l31 * 40 + hh * 8];
    h8 pf1 = *(const h8*)&PB[w][l31 * 40 + 16 + hh * 8];
    #pragma unroll
    for (int dt = 0; dt < 2; ++dt) {
      #pragma unroll
      for (int kg2 = 0; kg2 < 2; ++kg2) {
        int row = dt * 32 + l31;
        h8 vf = *(const h8*)&Vs[cur][row * 64 + SW(row, (kh32 >> 3) + kg2 * 2 + hh)];
        if (dt == 0) o0 = MF32(kg2 ? pf1 : pf0, vf, o0);
        else         o1 = MF32(kg2 ? pf1 : pf0, vf, o1);
      }
    }
    if (c < 15) {
      #pragma unroll
      for (int r = 0; r < 16; ++r) mw[r] = nmw[r];
    }
    __syncthreads();
  }

  // ---- epilogue: reduce l across 32 cols, combine k-halves via LDS ----
  #pragma unroll
  for (int r = 0; r < 16; ++r) {
    float v = lrow[r];
    v += __shfl_xor(v, 1);
    v += __shfl_xor(v, 2);
    v += __shfl_xor(v, 4);
    v += __shfl_xor(v, 8);
    v += __shfl_xor(v, 16);
    lrow[r] = v;
  }
  float* OB = (float*)&Ks[0][0];       // [64][64] f32 partials (16KB)
  float* LS = (float*)&PB[0][0];       // [64] f32 l partials
  if (kh32) {                           // waves 2,3 publish partials
    #pragma unroll
    for (int r = 0; r < 16; ++r) {
      int row = qh32 + (r & 3) + 8 * (r >> 2) + 4 * hh;
      OB[row * 64 + l31]      = o0[r];
      OB[row * 64 + 32 + l31] = o1[r];
      if (l31 == 0) LS[row] = lrow[r];
    }
  }
  __syncthreads();
  _Float16* OT = &Vs[0][0];            // [64][72] fp16 out tile
  if (!kh32) {                          // waves 0,1 combine + normalize
    #pragma unroll
    for (int r = 0; r < 16; ++r) {
      int row = qh32 + (r & 3) + 8 * (r >> 2) + 4 * hh;
      float inv = 1.0f / (lrow[r] + LS[row]);
      OT[row * 72 + l31]      = (_Float16)((o0[r] + OB[row * 64 + l31]) * inv);
      OT[row * 72 + 32 + l31] = (_Float16)((o1[r] + OB[row * 64 + 32 + l31]) * inv);
    }
  }
  __syncthreads();
  const int orow = t >> 2, oseg = (t & 3) * 16;
  _Float16* op = out + qkbase + (size_t)(s0 + orow) * 1024 + oseg;
  *(h8*)op       = *(h8*)&OT[orow * 72 + oseg];
  *(h8*)(op + 8) = *(h8*)&OT[orow * 72 + oseg + 8];
}

// ---------------------------------------------------------------------------
extern "C" void kernel_launch(void* const* d_in, const int* in_sizes, int n_in,
                              void* d_out, int out_size, void* d_ws, size_t ws_size,
                              hipStream_t stream) {
  const float* x     = (const float*)d_in[0];
  const int*   masks = (const int*)d_in[1];
  const int*   Hm    = (const int*)d_in[2];
  const int*   Bm    = (const int*)d_in[3];
  const float* fc    = (const float*)d_in[4];
  const float* fs    = (const float*)d_in[5];
  const float* wq    = (const float*)d_in[6];
  const float* wk    = (const float*)d_in[7];
  const float* wv    = (const float*)d_in[8];
  const float* wo    = (const float*)d_in[9];
  float* out = (float*)d_out;

  _Float16* xh   = (_Float16*)d_ws;          // 2M halfs
  _Float16* wqt  = xh + (1 << 21);           // 1M each
  _Float16* wkt  = wqt + (1 << 20);
  _Float16* wvt  = wkt + (1 << 20);
  _Float16* wot  = wvt + (1 << 20);
  _Float16* qhh  = wot + (1 << 20);          // 2M
  _Float16* khh  = qhh + (1 << 21);          // 2M
  _Float16* vth  = khh + (1 << 21);          // 2M
  _Float16* aoh  = vth + (1 << 21);          // 2M
  unsigned int* mpk = (unsigned int*)(aoh + (1 << 21));  // 64K words

  dim3 blk(256);
  prep<<<dim3(2304), blk, 0, stream>>>(x, wq, wk, wv, wo, masks,
                                       xh, wqt, wkt, wvt, wot, mpk);
  gemm_qkv16<<<dim3(8, 32, 3), blk, 0, stream>>>(xh, wqt, wkt, wvt,
                                                 qhh, khh, vth, Hm, Bm, fc, fs);
  attn_mfma<<<dim3(512), blk, 0, stream>>>(qhh, khh, vth, mpk, aoh);
  gemm_o16<<<dim3(8, 32), blk, 0, stream>>>(aoh, wot, out);
}

// Round 13
// 159.052 us; speedup vs baseline: 1.0252x; 1.0252x over previous
//
#include <hip/hip_runtime.h>

#define SLEN 1024
#define BATCH 2
#define DEPTH 6

typedef _Float16 h8 __attribute__((ext_vector_type(8)));
typedef float    f4 __attribute__((ext_vector_type(4)));
#define MF16(a, b, c) __builtin_amdgcn_mfma_f32_16x16x32_f16(a, b, c, 0, 0, 0)

// logical chunk <-> stored chunk swizzle (8 chunks of 8 halfs per 64-half row)
#define SW(row, c) ((((c) ^ ((row) & 7))) * 8)

// async global->LDS, 16B per lane; LDS dest = wave-uniform base + lane*16.
// NOTE (r8, r12 failures): keep <=6 outstanding issues per wave per barrier
// interval and single-buffer the GEMM staging — beyond that the barrier
// drain is not reliable (nondeterministic LDS contents).
__device__ __forceinline__ void async_cp16(const _Float16* g, _Float16* l) {
  __builtin_amdgcn_global_load_lds(
      (const __attribute__((address_space(1))) void*)g,
      (__attribute__((address_space(3))) void*)l, 16, 0, 0);
}

// ---------------------------------------------------------------------------
// prep: bid 0..1023 x->fp16 ; 1024..2047 weight transpose+convert ;
//       2048..2303 mask bit-pack
// ---------------------------------------------------------------------------
__global__ __launch_bounds__(256) void prep(const float* __restrict__ x,
    const float* __restrict__ wq, const float* __restrict__ wk,
    const float* __restrict__ wv, const float* __restrict__ wo,
    const int* __restrict__ masks, _Float16* __restrict__ xh,
    _Float16* __restrict__ qt, _Float16* __restrict__ kt,
    _Float16* __restrict__ vt, _Float16* __restrict__ ot,
    unsigned int* __restrict__ mpk) {
  __shared__ _Float16 T[64][72];
  const int bid = blockIdx.x, t = threadIdx.x;
  if (bid < 1024) {
    int idx = (bid * 256 + t) * 8;
    float4 f0 = *(const float4*)(x + idx);
    float4 f1 = *(const float4*)(x + idx + 4);
    union { h8 v; _Float16 e[8]; } u;
    u.e[0] = (_Float16)f0.x; u.e[1] = (_Float16)f0.y;
    u.e[2] = (_Float16)f0.z; u.e[3] = (_Float16)f0.w;
    u.e[4] = (_Float16)f1.x; u.e[5] = (_Float16)f1.y;
    u.e[6] = (_Float16)f1.z; u.e[7] = (_Float16)f1.w;
    *(h8*)(xh + idx) = u.v;
  } else if (bid < 2048) {
    const int i = bid - 1024;
    const int wsel = i >> 8;
    const float* W = wsel == 0 ? wq : wsel == 1 ? wk : wsel == 2 ? wv : wo;
    _Float16* O = wsel == 0 ? qt : wsel == 1 ? kt : wsel == 2 ? vt : ot;
    const int k0 = ((i >> 4) & 15) * 64, n0 = (i & 15) * 64;
    const int rr = t >> 2, cs = (t & 3) * 16;
    #pragma unroll
    for (int j = 0; j < 4; ++j) {
      float4 f = *(const float4*)(W + (size_t)(k0 + rr) * 1024 + n0 + cs + j * 4);
      T[rr][cs + j * 4 + 0] = (_Float16)f.x;
      T[rr][cs + j * 4 + 1] = (_Float16)f.y;
      T[rr][cs + j * 4 + 2] = (_Float16)f.z;
      T[rr][cs + j * 4 + 3] = (_Float16)f.w;
    }
    __syncthreads();
    const int n = t >> 2, ks = (t & 3) * 16;
    union { h8 v; _Float16 e[8]; } u0, u1;
    #pragma unroll
    for (int j = 0; j < 8; ++j) { u0.e[j] = T[ks + j][n]; u1.e[j] = T[ks + 8 + j][n]; }
    *(h8*)(O + (size_t)(n0 + n) * 1024 + k0 + ks)     = u0.v;
    *(h8*)(O + (size_t)(n0 + n) * 1024 + k0 + ks + 8) = u1.v;
  } else {
    const int g = (bid - 2048) * 256 + t;
    const int row = g >> 5, w = g & 31;
    const int* m = masks + (size_t)row * 1024 + w * 32;
    unsigned int bits = 0;
    #pragma unroll
    for (int j4 = 0; j4 < 8; ++j4) {
      int4 mm = *(const int4*)(m + j4 * 4);
      if (mm.x) bits |= 1u << (j4 * 4 + 0);
      if (mm.y) bits |= 1u << (j4 * 4 + 1);
      if (mm.z) bits |= 1u << (j4 * 4 + 2);
      if (mm.w) bits |= 1u << (j4 * 4 + 3);
    }
    mpk[g] = bits;
  }
}

// ---------------------------------------------------------------------------
// fp16 MFMA GEMM, 64x128 tile, BK=64, SINGLE-buffer async-LDS staging,
// 2 barriers per K-chunk (r9/r10 proven — do NOT double-buffer or widen,
// see race note above). SH passed in (24.5 KB). Wave-tile 32x64 (acc 2x4).
// TMODE 0: plain store. TMODE 1: V-transpose store.
// TMODE 2: fused RoPE epilogue (2 threads per (row,head), vv[32], fp32 math).
// ---------------------------------------------------------------------------
template <int TMODE, typename CT>
__device__ __forceinline__ void gemm16(const _Float16* __restrict__ A,
                                       const _Float16* __restrict__ Bt,
                                       CT* __restrict__ C,
                                       const int* __restrict__ Hm,
                                       const int* __restrict__ Bm,
                                       _Float16* __restrict__ SH,
                                       const float* __restrict__ FR) {
  _Float16* As = SH;            // 4096 halfs: 64 rows x 64
  _Float16* Bs = SH + 4096;     // 8192 halfs: 128 rows x 64
  const int t    = threadIdx.x;
  const int bm   = blockIdx.y * 64, bn = blockIdx.x * 128;
  const int w    = t >> 6, lane = t & 63;
  const int ln15 = lane & 15, quad = lane >> 4;
  const int wm   = (w >> 1) * 32, wn = (w & 1) * 64;

  // staging lane map: 8 rows x 8 chunks per issue; row&7 == lane>>3
  const int srow8 = lane >> 3;
  const int sch   = (lane & 7) ^ srow8;
  const _Float16* agp = A  + (size_t)(bm + w * 16 + srow8) * 1024 + sch * 8;
  const _Float16* bgp = Bt + (size_t)(bn + w * 32 + srow8) * 1024 + sch * 8;

  f4 acc[2][4];
  #pragma unroll
  for (int i = 0; i < 2; ++i)
    #pragma unroll
    for (int j = 0; j < 4; ++j) acc[i][j] = (f4){0.f, 0.f, 0.f, 0.f};

  for (int k0 = 0; k0 < 1024; k0 += 64) {
    #pragma unroll
    for (int j = 0; j < 2; ++j)
      async_cp16(agp + k0 + j * 8192, As + w * 1024 + j * 512);
    #pragma unroll
    for (int j = 0; j < 4; ++j)
      async_cp16(bgp + k0 + j * 8192, Bs + w * 2048 + j * 512);
    __syncthreads();   // drain async stage + all waves ready
    #pragma unroll
    for (int kk = 0; kk < 8; kk += 4) {
      h8 af[2], bf[4];
      #pragma unroll
      for (int i = 0; i < 2; ++i) {
        int row = wm + i * 16 + ln15;
        af[i] = *(const h8*)&As[row * 64 + SW(row, kk + quad)];
      }
      #pragma unroll
      for (int j = 0; j < 4; ++j) {
        int row = wn + j * 16 + ln15;
        bf[j] = *(const h8*)&Bs[row * 64 + SW(row, kk + quad)];
      }
      #pragma unroll
      for (int i = 0; i < 2; ++i)
        #pragma unroll
        for (int j = 0; j < 4; ++j)
          acc[i][j] = MF16(af[i], bf[j], acc[i][j]);
    }
    __syncthreads();   // all reads done before next chunk overwrites
  }

  if (TMODE == 0) {
    #pragma unroll
    for (int i = 0; i < 2; ++i) {
      int row = bm + wm + i * 16 + quad * 4;
      #pragma unroll
      for (int r = 0; r < 4; ++r)
        #pragma unroll
        for (int j = 0; j < 4; ++j)
          C[(size_t)(row + r) * 1024 + bn + wn + j * 16 + ln15] = (CT)acc[i][j][r];
    }
  } else if (TMODE == 1) {
    #pragma unroll
    for (int i = 0; i < 2; ++i) {
      int m0 = bm + wm + i * 16 + quad * 4;
      #pragma unroll
      for (int r = 0; r < 4; ++r) {
        int m = m0 + r;
        size_t base = ((size_t)(m >> 10) * 1024) * 1024 + (m & 1023);
        #pragma unroll
        for (int j = 0; j < 4; ++j)
          C[base + (size_t)(bn + wn + j * 16 + ln15) * 1024] = (CT)acc[i][j][r];
      }
    }
  } else {
    // ---- fused RoPE epilogue ----
    // acc -> EP = SH[0:8192) as [64][128] fp16, 8-half chunks XOR-swizzled
    // by row&15. (Safe: last K-chunk barrier passed, all As/Bs reads done.)
    _Float16* EP = SH;
    #pragma unroll
    for (int i = 0; i < 2; ++i)
      #pragma unroll
      for (int j = 0; j < 4; ++j) {
        int cl = wn + j * 16 + ln15;
        #pragma unroll
        for (int r = 0; r < 4; ++r) {
          int rl = wm + i * 16 + quad * 4 + r;
          EP[rl * 128 + (((cl >> 3) ^ (rl & 15)) << 3) + (cl & 7)] =
              (_Float16)acc[i][j][r];
        }
      }
    __syncthreads();
    // 2 threads per (row, head); part p owns head dims [16p,16p+16) u [32+16p,48+16p)
    const int row = t >> 2, head = (t >> 1) & 1, p = t & 1;
    const int bs = bm + row;              // b*1024 + s (64-row tiles never straddle batch)
    const int r15 = row & 15;
    float vv[32];
    #pragma unroll
    for (int cc = 0; cc < 4; ++cc) {
      int lc = head * 8 + 2 * p + (cc & 1) + (cc >> 1) * 4;
      union { h8 v; _Float16 e[8]; } u;
      u.v = *(const h8*)&EP[row * 128 + (lc ^ r15) * 8];
      #pragma unroll
      for (int e = 0; e < 8; ++e) vv[cc * 8 + e] = (float)u.e[e];
    }
    // vv[0:16]  = head dims [16p, 16p+16)   (rot_H pairs local; rot_B re-part)
    // vv[16:32] = head dims [32+16p, 48+16p) (rot_B im-part for vv[0:16])
    #pragma unroll 1
    for (int d = 0; d < DEPTH; ++d) {
      if (Hm[d * (BATCH * SLEN) + bs] != 0) {
        #pragma unroll
        for (int jj = 0; jj < 8; ++jj) {
          int j0 = 8 * p + jj, j1 = 16 + 8 * p + jj;
          float re0 = vv[2 * jj], im0 = vv[2 * jj + 1];
          vv[2 * jj]     = re0 * FR[j0] - im0 * FR[32 + j0];
          vv[2 * jj + 1] = re0 * FR[32 + j0] + im0 * FR[j0];
          float re1 = vv[16 + 2 * jj], im1 = vv[17 + 2 * jj];
          vv[16 + 2 * jj] = re1 * FR[j1] - im1 * FR[32 + j1];
          vv[17 + 2 * jj] = re1 * FR[32 + j1] + im1 * FR[j1];
        }
      }
      if (Bm[(d * 2 + 0) * (BATCH * SLEN) + bs] != 0) {
        #pragma unroll
        for (int jj = 0; jj < 16; ++jj) {
          int j = 16 * p + jj;
          float re = vv[jj], im = vv[16 + jj];
          vv[jj]      = re * FR[j] - im * FR[32 + j];
          vv[16 + jj] = re * FR[32 + j] + im * FR[j];
        }
      }
      if (Bm[(d * 2 + 1) * (BATCH * SLEN) + bs] != 0) {
        #pragma unroll
        for (int jj = 0; jj < 16; ++jj) {
          int j = 16 * p + jj;
          float re = vv[jj], im = vv[16 + jj];
          vv[jj]      = re * FR[64 + j] - im * FR[96 + j];
          vv[16 + jj] = re * FR[96 + j] + im * FR[64 + j];
        }
      }
    }
    _Float16* dst = (_Float16*)C + (size_t)(bm + row) * 1024 + bn + head * 64;
    #pragma unroll
    for (int cc = 0; cc < 4; ++cc) {
      union { h8 v; _Float16 e[8]; } u;
      #pragma unroll
      for (int e = 0; e < 8; ++e) u.e[e] = (_Float16)vv[cc * 8 + e];
      int off = (cc < 2) ? (16 * p + cc * 8) : (32 + 16 * p + (cc - 2) * 8);
      *(h8*)(dst + off) = u.v;
    }
  }
}

__global__ __launch_bounds__(256) void gemm_qkv16(
    const _Float16* __restrict__ xh, const _Float16* __restrict__ qt,
    const _Float16* __restrict__ kt, const _Float16* __restrict__ vtw,
    _Float16* __restrict__ q, _Float16* __restrict__ k,
    _Float16* __restrict__ vth, const int* __restrict__ Hm,
    const int* __restrict__ Bm, const float* __restrict__ fc,
    const float* __restrict__ fs) {
  __shared__ _Float16 SH[12288];
  __shared__ float FR[128];    // c1|s1|c2|s2
  if (blockIdx.z != 2 && threadIdx.x < 128) {
    int g = threadIdx.x & 31;
    FR[threadIdx.x] = (threadIdx.x < 32) ? fc[32 + g]
                    : (threadIdx.x < 64) ? fs[32 + g]
                    : (threadIdx.x < 96) ? fc[64 + g] : fs[64 + g];
  }
  if (blockIdx.z == 2)
    gemm16<1, _Float16>(xh, vtw, vth, nullptr, nullptr, SH, nullptr);
  else if (blockIdx.z == 1)
    gemm16<2, _Float16>(xh, kt, k, Hm, Bm, SH, FR);
  else
    gemm16<2, _Float16>(xh, qt, q, Hm, Bm, SH, FR);
}

__global__ __launch_bounds__(256) void gemm_o16(
    const _Float16* __restrict__ A, const _Float16* __restrict__ Bt,
    float* __restrict__ C) {
  __shared__ _Float16 SH[12288];
  gemm16<0, float>(A, Bt, C, nullptr, nullptr, SH, nullptr);
}

// ---------------------------------------------------------------------------
// MFMA flash attention — r10 proven version (16x16 MFMAs, dbuf async staging
// at 4 issues/wave, one barrier per chunk, bitpacked mask, fixed-shift
// softmax p=exp(s/8-3)). r11's 32x32 variant regressed; do not re-apply.
// ---------------------------------------------------------------------------
__global__ __launch_bounds__(256) void attn_mfma(const _Float16* __restrict__ qh,
    const _Float16* __restrict__ kh, const _Float16* __restrict__ vth,
    const unsigned int* __restrict__ mpk, _Float16* __restrict__ out) {
  __shared__ _Float16 Ks[2][64 * 64];
  __shared__ _Float16 Vs[2][64 * 64];
  __shared__ _Float16 QP[4][16][72];

  const int t    = threadIdx.x;
  const int w    = t >> 6, lane = t & 63;
  const int ln15 = lane & 15, quad = lane >> 4;

  const int bh = blockIdx.x & 31;       // same (b,h) -> same XCD
  const int s0 = (blockIdx.x >> 5) * 64;
  const int b = bh >> 4, h = bh & 15;
  const size_t qkbase = (size_t)b * (SLEN * 1024) + h * 64;
  const size_t vbase  = ((size_t)b * 1024 + h * 64) * SLEN;

  {
    const int srow = t >> 2, sc0 = (t & 3) * 16;
    const _Float16* src = qh + qkbase + (size_t)(s0 + srow) * 1024 + sc0;
    *(h8*)&QP[w][srow & 15][sc0]     = *(const h8*)src;
    *(h8*)&QP[w][srow & 15][sc0 + 8] = *(const h8*)(src + 8);
  }
  h8 aq0 = *(h8*)&QP[w][ln15][quad * 8];
  h8 aq1 = *(h8*)&QP[w][ln15][32 + quad * 8];

  const int srow8 = lane >> 3;
  const int sch   = (lane & 7) ^ srow8;
  const _Float16* kgp = kh + qkbase + (size_t)(w * 16 + srow8) * 1024 + sch * 8;
  const _Float16* vgp = vth + vbase + (size_t)(w * 16 + srow8) * 1024 + sch * 8;

  const unsigned int* mp = mpk + ((size_t)b * SLEN + s0 + w * 16 + quad * 4) * 32;

  float lrow[4] = {1e-30f, 1e-30f, 1e-30f, 1e-30f};
  f4 oacc[4];
  #pragma unroll
  for (int f = 0; f < 4; ++f) oacc[f] = (f4){0.f, 0.f, 0.f, 0.f};

  async_cp16(kgp,        &Ks[0][w * 1024]);
  async_cp16(kgp + 8192, &Ks[0][w * 1024 + 512]);
  async_cp16(vgp,        &Vs[0][w * 1024]);
  async_cp16(vgp + 8192, &Vs[0][w * 1024 + 512]);
  unsigned int w0[4], w1[4];
  #pragma unroll
  for (int r = 0; r < 4; ++r) { w0[r] = mp[r * 32]; w1[r] = mp[r * 32 + 1]; }
  __syncthreads();

  for (int c = 0; c < 16; ++c) {
    const int cur = c & 1;
    unsigned int nw0[4], nw1[4];
    if (c < 15) {
      const size_t ko = (size_t)((c + 1) * 64) * 1024;
      const int    vo = (c + 1) * 64;
      async_cp16(kgp + ko,        &Ks[cur ^ 1][w * 1024]);
      async_cp16(kgp + ko + 8192, &Ks[cur ^ 1][w * 1024 + 512]);
      async_cp16(vgp + vo,        &Vs[cur ^ 1][w * 1024]);
      async_cp16(vgp + vo + 8192, &Vs[cur ^ 1][w * 1024 + 512]);
      #pragma unroll
      for (int r = 0; r < 4; ++r) {
        nw0[r] = mp[r * 32 + (c + 1) * 2];
        nw1[r] = mp[r * 32 + (c + 1) * 2 + 1];
      }
    }

    f4 s[4];
    #pragma unroll
    for (int f = 0; f < 4; ++f) {
      int row = f * 16 + ln15;
      h8 bk0 = *(const h8*)&Ks[cur][row * 64 + SW(row, quad)];
      h8 bk1 = *(const h8*)&Ks[cur][row * 64 + SW(row, 4 + quad)];
      f4 acc = (f4){0.f, 0.f, 0.f, 0.f};
      acc = MF16(aq0, bk0, acc);
      acc = MF16(aq1, bk1, acc);
      s[f] = acc;
    }
    #pragma unroll
    for (int f = 0; f < 4; ++f) {
      const int col = f * 16 + ln15;
      #pragma unroll
      for (int r = 0; r < 4; ++r) {
        unsigned int wd = (col & 32) ? w1[r] : w0[r];
        float p = ((wd >> (col & 31)) & 1u)
                    ? __expf(s[f][r] * 0.125f - 3.0f) : 0.0f;
        lrow[r] += p;
        QP[w][quad * 4 + r][col] = (_Float16)p;
      }
    }
    h8 ap0 = *(h8*)&QP[w][ln15][quad * 8];
    h8 ap1 = *(h8*)&QP[w][ln15][32 + quad * 8];
    #pragma unroll
    for (int f = 0; f < 4; ++f) {
      int row = f * 16 + ln15;
      h8 bv0 = *(const h8*)&Vs[cur][row * 64 + SW(row, quad)];
      h8 bv1 = *(const h8*)&Vs[cur][row * 64 + SW(row, 4 + quad)];
      f4 o = oacc[f];
      o = MF16(ap0, bv0, o);
      o = MF16(ap1, bv1, o);
      oacc[f] = o;
    }
    if (c < 15) {
      #pragma unroll
      for (int r = 0; r < 4; ++r) { w0[r] = nw0[r]; w1[r] = nw1[r]; }
    }
    __syncthreads();
  }

  #pragma unroll
  for (int r = 0; r < 4; ++r) {
    float sm = lrow[r];
    sm += __shfl_xor(sm, 1);
    sm += __shfl_xor(sm, 2);
    sm += __shfl_xor(sm, 4);
    sm += __shfl_xor(sm, 8);
    lrow[r] = 1.0f / sm;
  }
  #pragma unroll
  for (int f = 0; f < 4; ++f)
    #pragma unroll
    for (int r = 0; r < 4; ++r)
      QP[w][quad * 4 + r][f * 16 + ln15] = (_Float16)(oacc[f][r] * lrow[r]);
  const int orow = lane >> 2, oseg = (lane & 3) * 16;
  _Float16* op = out + qkbase + (size_t)(s0 + w * 16 + orow) * 1024 + oseg;
  *(h8*)op       = *(h8*)&QP[w][orow][oseg];
  *(h8*)(op + 8) = *(h8*)&QP[w][orow][oseg + 8];
}

// ---------------------------------------------------------------------------
extern "C" void kernel_launch(void* const* d_in, const int* in_sizes, int n_in,
                              void* d_out, int out_size, void* d_ws, size_t ws_size,
                              hipStream_t stream) {
  const float* x     = (const float*)d_in[0];
  const int*   masks = (const int*)d_in[1];
  const int*   Hm    = (const int*)d_in[2];
  const int*   Bm    = (const int*)d_in[3];
  const float* fc    = (const float*)d_in[4];
  const float* fs    = (const float*)d_in[5];
  const float* wq    = (const float*)d_in[6];
  const float* wk    = (const float*)d_in[7];
  const float* wv    = (const float*)d_in[8];
  const float* wo    = (const float*)d_in[9];
  float* out = (float*)d_out;

  _Float16* xh   = (_Float16*)d_ws;          // 2M halfs
  _Float16* wqt  = xh + (1 << 21);           // 1M each
  _Float16* wkt  = wqt + (1 << 20);
  _Float16* wvt  = wkt + (1 << 20);
  _Float16* wot  = wvt + (1 << 20);
  _Float16* qhh  = wot + (1 << 20);          // 2M
  _Float16* khh  = qhh + (1 << 21);          // 2M
  _Float16* vth  = khh + (1 << 21);          // 2M
  _Float16* aoh  = vth + (1 << 21);          // 2M
  unsigned int* mpk = (unsigned int*)(aoh + (1 << 21));  // 64K words

  dim3 blk(256);
  prep<<<dim3(2304), blk, 0, stream>>>(x, wq, wk, wv, wo, masks,
                                       xh, wqt, wkt, wvt, wot, mpk);
  gemm_qkv16<<<dim3(8, 32, 3), blk, 0, stream>>>(xh, wqt, wkt, wvt,
                                                 qhh, khh, vth, Hm, Bm, fc, fs);
  attn_mfma<<<dim3(512), blk, 0, stream>>>(qhh, khh, vth, mpk, aoh);
  gemm_o16<<<dim3(8, 32), blk, 0, stream>>>(aoh, wot, out);
}